// Round 3
// baseline (220.711 us; speedup 1.0000x reference)
//
#include <hip/hip_runtime.h>
#include <hip/hip_cooperative_groups.h>
#include <limits.h>

namespace cg = cooperative_groups;

#define ID_MAX 4096
#define SLICES 16
#define SLICE_W (ID_MAX / SLICES)   // 256 ids per slice == block size
#define FUSED_BLOCKS 1024           // 4 blocks/CU guaranteed by launch_bounds
#define POOL_BLOCKS 256

typedef float vf4 __attribute__((ext_vector_type(4)));

__device__ __forceinline__ int seg_search(const int* sptr, int B, int i) {
    if (i < sptr[0] || i >= sptr[B]) return -1;
    int lo = 0, hi = B;
    while (hi - lo > 1) {
        int mid = (lo + hi) >> 1;
        if (sptr[mid] <= i) lo = mid; else hi = mid;
    }
    return lo;
}

// ---------------------------------------------------------------------------
// Fused single-launch kernel (cooperative):
//   phase 0: blocks [0, B*SLICES) build table slices in LDS (atomicMin) and
//            zero graph_out (s==0). Tiny: ~1.5 us.
//   grid.sync()  -- makes table + zeroed graph_out visible device-wide
//   phase 1: blocks [0, POOL_BLOCKS)  : segment-sum pool (identical to the
//                                        previously measured K2 pool path)
//            blocks [POOL_BLOCKS, ..) : grid-stride table-lookup gather
// Removes the K1->K2 dispatch serialization (~3-5 us) while preserving the
// pool/gather co-execution that the fused K2 already had.
// ---------------------------------------------------------------------------
__global__ void __launch_bounds__(256, 4)
fused_all(const int* __restrict__ node_index,
          const int* __restrict__ ptr,
          int* __restrict__ table,
          const vf4* __restrict__ x4,
          const int* __restrict__ input_ids,
          float* __restrict__ graph_out,
          vf4* __restrict__ out4,
          int N, int B, int D, int vpr, int vshift, int L,
          int rows_pb, long long total_vec) {
    __shared__ int sptr[64];
    __shared__ vf4 red[256];
    __shared__ int ltab[SLICE_W];

    const int tid = threadIdx.x;
    const int bid = blockIdx.x;

    // ---------------- phase 0: table build + graph_out zero ----------------
    if (bid < B * SLICES) {
        const int b  = bid >> 4;               // / SLICES (SLICES == 16)
        const int s  = bid & (SLICES - 1);
        const int lo = s * SLICE_W;
        const int start = ptr[b];
        const int end   = ptr[b + 1];

        ltab[tid] = INT_MAX;
        __syncthreads();
        for (int i = start + tid; i < end; i += 256) {
            int id = node_index[i];
            unsigned rel = (unsigned)(id - lo); // wraps for id<lo / OOR
            if (rel < SLICE_W)
                atomicMin(&ltab[rel], i - start);
        }
        __syncthreads();
        table[(size_t)b * ID_MAX + lo + tid] = ltab[tid];

        if (s == 0) {
            float* go = graph_out + (size_t)b * D;
            for (int i = tid; i < D; i += 256) go[i] = 0.0f;
        }
    }

    cg::this_grid().sync();

    // ---------------- phase 1: pool + gather (co-executing roles) ----------
    if (bid < POOL_BLOCKS) {
        if (tid <= B) sptr[tid] = ptr[tid];
        __syncthreads();

        const int rows_per_iter = 256 / vpr;   // vpr divides 256 (host-checked)
        const int c    = tid & (vpr - 1);
        const int rsub = tid / vpr;

        const int r0 = bid * rows_pb;
        const int r1 = min(r0 + rows_pb, N);
        if (r0 >= r1) return;

        const int b_first = seg_search(sptr, B, r0);
        const int b_last  = seg_search(sptr, B, r1 - 1);

        if (b_first == b_last && b_first >= 0) {
            // fast path: whole chunk inside one graph -> pure streaming
            vf4 acc = 0.0f;
            for (int i = r0 + rsub; i < r1; i += rows_per_iter)
                acc += __builtin_nontemporal_load(&x4[(size_t)i * vpr + c]);
            red[tid] = acc;
            __syncthreads();
            if (rsub == 0) {
                for (int k = 1; k < rows_per_iter; ++k)
                    acc += red[k * vpr + c];
                float* dst = &graph_out[(size_t)b_first * D + c * 4];
                atomicAdd(dst + 0, acc.x);
                atomicAdd(dst + 1, acc.y);
                atomicAdd(dst + 2, acc.z);
                atomicAdd(dst + 3, acc.w);
            }
        } else {
            // generic path: chunk crosses a boundary (~16 of 256 blocks)
            vf4 acc = 0.0f;
            int accb = -1;
            for (int i = r0 + rsub; i < r1; i += rows_per_iter) {
                int b = seg_search(sptr, B, i);
                if (b != accb) {
                    if (accb >= 0) {
                        float* dst = &graph_out[(size_t)accb * D + c * 4];
                        atomicAdd(dst + 0, acc.x);
                        atomicAdd(dst + 1, acc.y);
                        atomicAdd(dst + 2, acc.z);
                        atomicAdd(dst + 3, acc.w);
                    }
                    acc = 0.0f;
                    accb = b;
                }
                if (b >= 0) acc += x4[(size_t)i * vpr + c];
            }
            if (accb >= 0) {
                float* dst = &graph_out[(size_t)accb * D + c * 4];
                atomicAdd(dst + 0, acc.x);
                atomicAdd(dst + 1, acc.y);
                atomicAdd(dst + 2, acc.z);
                atomicAdd(dst + 3, acc.w);
            }
        }
    } else {
        // grid-stride gather over total_vec float4 elements
        const long long stride = (long long)(FUSED_BLOCKS - POOL_BLOCKS) * 256;
        for (long long t = (long long)(bid - POOL_BLOCKS) * 256 + tid;
             t < total_vec; t += stride) {
            int row = (int)(t >> vshift);      // flattened (b,l)
            int c   = (int)(t & (vpr - 1));
            int b   = row / L;
            int id  = input_ids[row];
            int m   = (id >= 0 && id < ID_MAX) ? table[(size_t)b * ID_MAX + id]
                                               : INT_MAX;
            vf4 v = 0.0f;
            if (m != INT_MAX)
                v = x4[(long long)m * vpr + c];  // row m used GLOBALLY (faithful
                                                 // to reference's quirk)
            __builtin_nontemporal_store(v, &out4[t]);
        }
    }
}

// ---------------------------------------------------------------------------
// Fallback two-kernel path (used if cooperative launch is unavailable) --
// byte-identical to the previously measured 103.6 us configuration.
// ---------------------------------------------------------------------------
__global__ void __launch_bounds__(256)
build_table_sliced(const int* __restrict__ node_index,
                   const int* __restrict__ ptr,
                   int* __restrict__ table,
                   float* __restrict__ graph_out,
                   int D) {
    __shared__ int ltab[SLICE_W];
    const int b   = blockIdx.x >> 4;
    const int s   = blockIdx.x & (SLICES - 1);
    const int tid = threadIdx.x;
    const int lo  = s * SLICE_W;
    const int start = ptr[b];
    const int end   = ptr[b + 1];

    ltab[tid] = INT_MAX;
    __syncthreads();

    for (int i = start + tid; i < end; i += 256) {
        int id = node_index[i];
        unsigned rel = (unsigned)(id - lo);
        if (rel < SLICE_W)
            atomicMin(&ltab[rel], i - start);
    }
    __syncthreads();

    table[(size_t)b * ID_MAX + lo + tid] = ltab[tid];

    if (s == 0) {
        float* go = graph_out + (size_t)b * D;
        for (int i = tid; i < D; i += 256) go[i] = 0.0f;
    }
}

__global__ void pool_gather_fused(const vf4* __restrict__ x4,
                                  const int* __restrict__ ptr,
                                  const int* __restrict__ input_ids,
                                  const int* __restrict__ table,
                                  float* __restrict__ graph_out,
                                  vf4* __restrict__ out4,
                                  int N, int B, int D, int vpr, int vshift, int L,
                                  int pool_blocks, int rows_pb,
                                  long long total_vec) {
    const int tid = threadIdx.x;

    if ((int)blockIdx.x < pool_blocks) {
        __shared__ int sptr[64];
        __shared__ vf4 red[256];
        if (tid <= B) sptr[tid] = ptr[tid];
        __syncthreads();

        const int rows_per_iter = 256 / vpr;
        const int c    = tid & (vpr - 1);
        const int rsub = tid / vpr;

        const int r0 = blockIdx.x * rows_pb;
        const int r1 = min(r0 + rows_pb, N);
        if (r0 >= r1) return;

        const int b_first = seg_search(sptr, B, r0);
        const int b_last  = seg_search(sptr, B, r1 - 1);

        if (b_first == b_last && b_first >= 0) {
            vf4 acc = 0.0f;
            for (int i = r0 + rsub; i < r1; i += rows_per_iter)
                acc += __builtin_nontemporal_load(&x4[(size_t)i * vpr + c]);
            red[tid] = acc;
            __syncthreads();
            if (rsub == 0) {
                for (int k = 1; k < rows_per_iter; ++k)
                    acc += red[k * vpr + c];
                float* dst = &graph_out[(size_t)b_first * D + c * 4];
                atomicAdd(dst + 0, acc.x);
                atomicAdd(dst + 1, acc.y);
                atomicAdd(dst + 2, acc.z);
                atomicAdd(dst + 3, acc.w);
            }
        } else {
            vf4 acc = 0.0f;
            int accb = -1;
            for (int i = r0 + rsub; i < r1; i += rows_per_iter) {
                int b = seg_search(sptr, B, i);
                if (b != accb) {
                    if (accb >= 0) {
                        float* dst = &graph_out[(size_t)accb * D + c * 4];
                        atomicAdd(dst + 0, acc.x);
                        atomicAdd(dst + 1, acc.y);
                        atomicAdd(dst + 2, acc.z);
                        atomicAdd(dst + 3, acc.w);
                    }
                    acc = 0.0f;
                    accb = b;
                }
                if (b >= 0) acc += x4[(size_t)i * vpr + c];
            }
            if (accb >= 0) {
                float* dst = &graph_out[(size_t)accb * D + c * 4];
                atomicAdd(dst + 0, acc.x);
                atomicAdd(dst + 1, acc.y);
                atomicAdd(dst + 2, acc.z);
                atomicAdd(dst + 3, acc.w);
            }
        }
    } else {
        long long t = (long long)(blockIdx.x - pool_blocks) * blockDim.x + tid;
        if (t >= total_vec) return;
        int row = (int)(t >> vshift);
        int c   = (int)(t & (vpr - 1));
        int b   = row / L;
        int id  = input_ids[row];
        int m   = (id >= 0 && id < ID_MAX) ? table[(size_t)b * ID_MAX + id]
                                           : INT_MAX;
        vf4 v = 0.0f;
        if (m != INT_MAX)
            v = x4[(long long)m * vpr + c];
        __builtin_nontemporal_store(v, &out4[t]);
    }
}

// ---------------------------------------------------------------------------
// Scalar fallback kernels (odd D etc.)
// ---------------------------------------------------------------------------
__global__ void init_kernel(int* __restrict__ table, float* __restrict__ graph_out,
                            int table_n, int graph_n) {
    int i = blockIdx.x * blockDim.x + threadIdx.x;
    if (i < table_n) table[i] = INT_MAX;
    if (i < graph_n) graph_out[i] = 0.0f;
}

__global__ void build_table_kernel(const int* __restrict__ node_index,
                                   const int* __restrict__ ptr,
                                   int* __restrict__ table, int N, int B) {
    __shared__ int sptr[64];
    if (threadIdx.x <= B) sptr[threadIdx.x] = ptr[threadIdx.x];
    __syncthreads();
    int i = blockIdx.x * blockDim.x + threadIdx.x;
    if (i >= N) return;
    int b = seg_search(sptr, B, i);
    if (b < 0) return;
    int m = i - sptr[b];
    int id = node_index[i];
    if (id >= 0 && id < ID_MAX)
        atomicMin(&table[b * ID_MAX + id], m);
}

__global__ void pool1_kernel(const float* __restrict__ x,
                             const int* __restrict__ ptr,
                             float* __restrict__ graph_out,
                             int N, int B, int D, int rows_per_block) {
    __shared__ int sptr[64];
    if (threadIdx.x <= B) sptr[threadIdx.x] = ptr[threadIdx.x];
    __syncthreads();
    int d = threadIdx.x;
    if (d >= D) return;
    int r0 = blockIdx.x * rows_per_block;
    int r1 = min(r0 + rows_per_block, N);
    float acc = 0.0f;
    int accb = -1;
    for (int i = r0; i < r1; ++i) {
        int b = seg_search(sptr, B, i);
        if (b != accb) {
            if (accb >= 0) atomicAdd(&graph_out[(size_t)accb * D + d], acc);
            acc = 0.0f; accb = b;
        }
        if (b >= 0) acc += x[(size_t)i * D + d];
    }
    if (accb >= 0) atomicAdd(&graph_out[(size_t)accb * D + d], acc);
}

__global__ void gather1_kernel(const int* __restrict__ input_ids,
                               const int* __restrict__ table,
                               const float* __restrict__ x,
                               float* __restrict__ seq_out,
                               long long total, int D, int L) {
    long long t = (long long)blockIdx.x * blockDim.x + threadIdx.x;
    if (t >= total) return;
    long long row = t / D;
    int c = (int)(t - row * D);
    int b = (int)(row / L);
    int id = input_ids[row];
    int m  = (id >= 0 && id < ID_MAX) ? table[(size_t)b * ID_MAX + id] : INT_MAX;
    seq_out[t] = (m != INT_MAX) ? x[(long long)m * D + c] : 0.0f;
}

extern "C" void kernel_launch(void* const* d_in, const int* in_sizes, int n_in,
                              void* d_out, int out_size, void* d_ws, size_t ws_size,
                              hipStream_t stream) {
    const int*   input_ids  = (const int*)  d_in[0];   // [B, L]
    const int*   node_index = (const int*)  d_in[1];   // [N]
    const float* x          = (const float*)d_in[2];   // [N, D]
    const int*   ptr        = (const int*)  d_in[3];   // [B+1]

    const int BL = in_sizes[0];
    const int N  = in_sizes[1];
    const int D  = in_sizes[2] / N;
    const int B  = in_sizes[3] - 1;
    const int L  = BL / B;

    float* seq_out   = (float*)d_out;                    // [B*L*D]
    float* graph_out = (float*)d_out + (size_t)BL * D;   // [B*D]
    int*   table     = (int*)d_ws;                       // [B * ID_MAX]

    const int vpr = D >> 2;                              // float4 per row
    const bool vec_ok = ((D & 3) == 0) && (vpr > 0) && (vpr <= 256) &&
                        (256 % vpr == 0) && (B >= 1) && (B <= 63);

    if (vec_ok) {
        int vshift = 0;
        while ((1 << vshift) < vpr) ++vshift;            // vpr is a power of 2
        int rows_pb = (N + POOL_BLOCKS - 1) / POOL_BLOCKS;
        long long total_vec = (long long)BL * vpr;

        // ---- preferred: single cooperative launch (phase0 -> sync -> phase1)
        const vf4* x4   = (const vf4*)x;
        vf4*       out4 = (vf4*)seq_out;
        int nN = N, nB = B, nD = D, nvpr = vpr, nvs = vshift, nL = L,
            nrpb = rows_pb;
        long long ntv = total_vec;
        void* args[] = {
            (void*)&node_index, (void*)&ptr, (void*)&table, (void*)&x4,
            (void*)&input_ids, (void*)&graph_out, (void*)&out4,
            (void*)&nN, (void*)&nB, (void*)&nD, (void*)&nvpr, (void*)&nvs,
            (void*)&nL, (void*)&nrpb, (void*)&ntv
        };
        hipError_t e = hipLaunchCooperativeKernel((const void*)fused_all,
                                                  dim3(FUSED_BLOCKS), dim3(256),
                                                  args, 0, stream);
        if (e == hipSuccess) return;
        (void)hipGetLastError();   // clear sticky error, take fallback path

        // ---- fallback: previously measured two-kernel path
        build_table_sliced<<<B * SLICES, 256, 0, stream>>>(node_index, ptr,
                                                           table, graph_out, D);
        const int gather_blocks = (int)((total_vec + 255) / 256);
        pool_gather_fused<<<POOL_BLOCKS + gather_blocks, 256, 0, stream>>>(
            x4, ptr, input_ids, table, graph_out, out4,
            N, B, D, vpr, vshift, L, POOL_BLOCKS, rows_pb, total_vec);
    } else {
        const int table_n = B * ID_MAX;
        const int graph_n = B * D;
        const int init_n  = table_n > graph_n ? table_n : graph_n;
        init_kernel<<<(init_n + 255) / 256, 256, 0, stream>>>(table, graph_out,
                                                              table_n, graph_n);
        build_table_kernel<<<(N + 255) / 256, 256, 0, stream>>>(node_index, ptr,
                                                                table, N, B);
        const int rows_per_block = 128;
        const int nchunks = (N + rows_per_block - 1) / rows_per_block;
        int bs = D < 1024 ? ((D + 63) / 64) * 64 : 1024;
        pool1_kernel<<<nchunks, bs, 0, stream>>>(x, ptr, graph_out, N, B, D,
                                                 rows_per_block);
        const long long total = (long long)BL * D;
        const int blocks = (int)((total + 255) / 256);
        gather1_kernel<<<blocks, 256, 0, stream>>>(input_ids, table, x,
                                                   seq_out, total, D, L);
    }
}

// Round 4
// 101.637 us; speedup vs baseline: 2.1716x; 2.1716x over previous
//
#include <hip/hip_runtime.h>
#include <limits.h>

#define ID_MAX 4096
#define SLICES 16                    // table slices per graph
#define SLICE_W (ID_MAX / SLICES)    // 256 ids per slice == block size
#define CPG 16                       // pool chunks per graph (boundary-aligned)

typedef float vf4 __attribute__((ext_vector_type(4)));

// ---------------------------------------------------------------------------
// Kernel A: table build + pool partials, one launch, independent block roles.
//   blocks [0, B*SLICES)          : per-(graph, id-slice) first-occurrence
//                                   table via LDS atomicMin (1 KB slice).
//   blocks [B*SLICES, +B*CPG)     : pool chunk (b, j) = j-th 1/CPG of graph
//                                   b's rows -- chunks NEVER cross a graph
//                                   boundary, so the partial sum is written
//                                   with a plain store (no atomics, no
//                                   zero-init, no seg_search).
// ---------------------------------------------------------------------------
__global__ void __launch_bounds__(256)
table_pool_kernel(const int* __restrict__ node_index,
                  const int* __restrict__ ptr,
                  int* __restrict__ table,
                  const vf4* __restrict__ x4,
                  vf4* __restrict__ partials,   // [B*CPG, vpr] vf4
                  int B, int vpr) {
    __shared__ int ltab[SLICE_W];
    __shared__ vf4 red[256];
    const int tid = threadIdx.x;
    const int bid = blockIdx.x;
    const int TB  = B * SLICES;

    if (bid < TB) {
        // ---- table slice ----
        const int b  = bid >> 4;               // / SLICES (== 16)
        const int s  = bid & (SLICES - 1);
        const int lo = s * SLICE_W;
        const int start = ptr[b];
        const int end   = ptr[b + 1];

        ltab[tid] = INT_MAX;
        __syncthreads();
        for (int i = start + tid; i < end; i += 256) {
            int id = node_index[i];
            unsigned rel = (unsigned)(id - lo); // wraps for id<lo / OOR
            if (rel < SLICE_W)
                atomicMin(&ltab[rel], i - start);
        }
        __syncthreads();
        table[(size_t)b * ID_MAX + lo + tid] = ltab[tid];
    } else {
        // ---- pool chunk (pure streaming, boundary-aligned) ----
        const int pid = bid - TB;
        const int b   = pid >> 4;              // / CPG (== 16)
        const int j   = pid & (CPG - 1);
        const int start = ptr[b];
        const int end   = ptr[b + 1];
        const int len   = end - start;
        const int sz    = (len + CPG - 1) / CPG;
        const int r0    = start + j * sz;
        const int r1    = min(r0 + sz, end);

        const int rows_per_iter = 256 / vpr;   // vpr divides 256 (host-checked)
        const int c    = tid & (vpr - 1);
        const int rsub = tid / vpr;

        vf4 acc = 0.0f;
        for (int i = r0 + rsub; i < r1; i += rows_per_iter)
            acc += __builtin_nontemporal_load(&x4[(size_t)i * vpr + c]);
        red[tid] = acc;
        __syncthreads();
        if (rsub == 0) {
            for (int k = 1; k < rows_per_iter; ++k)
                acc += red[k * vpr + c];
            partials[(size_t)pid * vpr + c] = acc;   // plain store
        }
    }
}

// ---------------------------------------------------------------------------
// Kernel B: gather + partial reduce, one launch, independent block roles.
//   blocks [0, B)   : graph_out[b] = sum of B's CPG partials (plain stores,
//                     deterministic order).
//   blocks [B, ...) : table-lookup gather, one vf4 per thread (same logic as
//                     the previously measured K2 gather path).
// ---------------------------------------------------------------------------
__global__ void __launch_bounds__(256)
gather_reduce_kernel(const int* __restrict__ input_ids,
                     const int* __restrict__ table,
                     const vf4* __restrict__ x4,
                     const float* __restrict__ partials,
                     float* __restrict__ graph_out,
                     vf4* __restrict__ out4,
                     int B, int D, int vpr, int vshift, int L,
                     long long total_vec) {
    const int tid = threadIdx.x;
    const int bid = blockIdx.x;

    if (bid < B) {
        // ---- reduce partials for graph bid ----
        const float* p = partials + (size_t)bid * CPG * D;
        for (int d = tid; d < D; d += 256) {
            float s = 0.0f;
            #pragma unroll
            for (int j = 0; j < CPG; ++j) s += p[(size_t)j * D + d];
            graph_out[(size_t)bid * D + d] = s;
        }
    } else {
        // ---- gather ----
        long long t = (long long)(bid - B) * 256 + tid;
        if (t >= total_vec) return;
        int row = (int)(t >> vshift);          // flattened (b,l)
        int c   = (int)(t & (vpr - 1));
        int b   = row / L;
        int id  = input_ids[row];
        int m   = (id >= 0 && id < ID_MAX) ? table[(size_t)b * ID_MAX + id]
                                           : INT_MAX;
        vf4 v = 0.0f;
        if (m != INT_MAX)
            v = x4[(long long)m * vpr + c];    // row m used GLOBALLY (faithful
                                               // to reference's quirk)
        __builtin_nontemporal_store(v, &out4[t]);
    }
}

// ---------------------------------------------------------------------------
// Scalar fallback kernels (odd D etc.)
// ---------------------------------------------------------------------------
__device__ __forceinline__ int seg_search(const int* sptr, int B, int i) {
    if (i < sptr[0] || i >= sptr[B]) return -1;
    int lo = 0, hi = B;
    while (hi - lo > 1) {
        int mid = (lo + hi) >> 1;
        if (sptr[mid] <= i) lo = mid; else hi = mid;
    }
    return lo;
}

__global__ void init_kernel(int* __restrict__ table, float* __restrict__ graph_out,
                            int table_n, int graph_n) {
    int i = blockIdx.x * blockDim.x + threadIdx.x;
    if (i < table_n) table[i] = INT_MAX;
    if (i < graph_n) graph_out[i] = 0.0f;
}

__global__ void build_table_kernel(const int* __restrict__ node_index,
                                   const int* __restrict__ ptr,
                                   int* __restrict__ table, int N, int B) {
    __shared__ int sptr[64];
    if (threadIdx.x <= B) sptr[threadIdx.x] = ptr[threadIdx.x];
    __syncthreads();
    int i = blockIdx.x * blockDim.x + threadIdx.x;
    if (i >= N) return;
    int b = seg_search(sptr, B, i);
    if (b < 0) return;
    int m = i - sptr[b];
    int id = node_index[i];
    if (id >= 0 && id < ID_MAX)
        atomicMin(&table[b * ID_MAX + id], m);
}

__global__ void pool1_kernel(const float* __restrict__ x,
                             const int* __restrict__ ptr,
                             float* __restrict__ graph_out,
                             int N, int B, int D, int rows_per_block) {
    __shared__ int sptr[64];
    if (threadIdx.x <= B) sptr[threadIdx.x] = ptr[threadIdx.x];
    __syncthreads();
    int d = threadIdx.x;
    if (d >= D) return;
    int r0 = blockIdx.x * rows_per_block;
    int r1 = min(r0 + rows_per_block, N);
    float acc = 0.0f;
    int accb = -1;
    for (int i = r0; i < r1; ++i) {
        int b = seg_search(sptr, B, i);
        if (b != accb) {
            if (accb >= 0) atomicAdd(&graph_out[(size_t)accb * D + d], acc);
            acc = 0.0f; accb = b;
        }
        if (b >= 0) acc += x[(size_t)i * D + d];
    }
    if (accb >= 0) atomicAdd(&graph_out[(size_t)accb * D + d], acc);
}

__global__ void gather1_kernel(const int* __restrict__ input_ids,
                               const int* __restrict__ table,
                               const float* __restrict__ x,
                               float* __restrict__ seq_out,
                               long long total, int D, int L) {
    long long t = (long long)blockIdx.x * blockDim.x + threadIdx.x;
    if (t >= total) return;
    long long row = t / D;
    int c = (int)(t - row * D);
    int b = (int)(row / L);
    int id = input_ids[row];
    int m  = (id >= 0 && id < ID_MAX) ? table[(size_t)b * ID_MAX + id] : INT_MAX;
    seq_out[t] = (m != INT_MAX) ? x[(long long)m * D + c] : 0.0f;
}

extern "C" void kernel_launch(void* const* d_in, const int* in_sizes, int n_in,
                              void* d_out, int out_size, void* d_ws, size_t ws_size,
                              hipStream_t stream) {
    const int*   input_ids  = (const int*)  d_in[0];   // [B, L]
    const int*   node_index = (const int*)  d_in[1];   // [N]
    const float* x          = (const float*)d_in[2];   // [N, D]
    const int*   ptr        = (const int*)  d_in[3];   // [B+1]

    const int BL = in_sizes[0];
    const int N  = in_sizes[1];
    const int D  = in_sizes[2] / N;
    const int B  = in_sizes[3] - 1;
    const int L  = BL / B;

    float* seq_out   = (float*)d_out;                    // [B*L*D]
    float* graph_out = (float*)d_out + (size_t)BL * D;   // [B*D]
    int*   table     = (int*)d_ws;                       // [B * ID_MAX]
    float* partials  = (float*)d_ws + (size_t)B * ID_MAX; // [B*CPG*D]

    const int vpr = D >> 2;                              // float4 per row
    const bool ws_ok  = ws_size >= ((size_t)B * ID_MAX + (size_t)B * CPG * D)
                                   * sizeof(float);
    const bool vec_ok = ((D & 3) == 0) && (vpr > 0) && (vpr <= 256) &&
                        (256 % vpr == 0) && (B >= 1) && (B <= 63) && ws_ok;

    if (vec_ok) {
        int vshift = 0;
        while ((1 << vshift) < vpr) ++vshift;            // vpr is a power of 2
        const long long total_vec = (long long)BL * vpr;

        // A: table build (B*SLICES blocks) + boundary-aligned pool partials
        //    (B*CPG blocks), independent roles, no ordering requirement.
        table_pool_kernel<<<B * SLICES + B * CPG, 256, 0, stream>>>(
            node_index, ptr, table, (const vf4*)x, (vf4*)partials, B, vpr);

        // B: partial reduce (B blocks) + gather (one vf4/thread).
        const int gather_blocks = (int)((total_vec + 255) / 256);
        gather_reduce_kernel<<<B + gather_blocks, 256, 0, stream>>>(
            input_ids, table, (const vf4*)x, partials, graph_out,
            (vf4*)seq_out, B, D, vpr, vshift, L, total_vec);
    } else {
        const int table_n = B * ID_MAX;
        const int graph_n = B * D;
        const int init_n  = table_n > graph_n ? table_n : graph_n;
        init_kernel<<<(init_n + 255) / 256, 256, 0, stream>>>(table, graph_out,
                                                              table_n, graph_n);
        build_table_kernel<<<(N + 255) / 256, 256, 0, stream>>>(node_index, ptr,
                                                                table, N, B);
        const int rows_per_block = 128;
        const int nchunks = (N + rows_per_block - 1) / rows_per_block;
        int bs = D < 1024 ? ((D + 63) / 64) * 64 : 1024;
        pool1_kernel<<<nchunks, bs, 0, stream>>>(x, ptr, graph_out, N, B, D,
                                                 rows_per_block);
        const long long total = (long long)BL * D;
        const int blocks = (int)((total + 255) / 256);
        gather1_kernel<<<blocks, 256, 0, stream>>>(input_ids, table, x,
                                                   seq_out, total, D, L);
    }
}

// Round 5
// 95.039 us; speedup vs baseline: 2.3223x; 1.0694x over previous
//
#include <hip/hip_runtime.h>
#include <limits.h>

#define ID_MAX 4096
#define SLICES 16                    // table slices per graph
#define SLICE_W (ID_MAX / SLICES)    // 256 ids per slice == block size
#define CPG 64                       // pool chunks per graph (boundary-aligned)
                                     // 16->64: 256->1024 pool blocks, for HBM
                                     // latency hiding on the 24.6 MB stream

typedef float vf4 __attribute__((ext_vector_type(4)));

// ---------------------------------------------------------------------------
// Kernel A: table build + pool partials, one launch, independent block roles.
//   blocks [0, B*SLICES)          : per-(graph, id-slice) first-occurrence
//                                   table via LDS atomicMin (1 KB slice).
//   blocks [B*SLICES, +B*CPG)     : pool chunk (b, j) = j-th 1/CPG of graph
//                                   b's rows -- chunks NEVER cross a graph
//                                   boundary, so the partial sum is written
//                                   with a plain store (no atomics, no
//                                   zero-init, no seg_search).
// ---------------------------------------------------------------------------
__global__ void __launch_bounds__(256)
table_pool_kernel(const int* __restrict__ node_index,
                  const int* __restrict__ ptr,
                  int* __restrict__ table,
                  const vf4* __restrict__ x4,
                  vf4* __restrict__ partials,   // [B*CPG, vpr] vf4
                  int B, int vpr) {
    __shared__ int ltab[SLICE_W];
    __shared__ vf4 red[256];
    const int tid = threadIdx.x;
    const int bid = blockIdx.x;
    const int TB  = B * SLICES;

    if (bid < TB) {
        // ---- table slice ----
        const int b  = bid >> 4;               // / SLICES (== 16)
        const int s  = bid & (SLICES - 1);
        const int lo = s * SLICE_W;
        const int start = ptr[b];
        const int end   = ptr[b + 1];

        ltab[tid] = INT_MAX;
        __syncthreads();
        for (int i = start + tid; i < end; i += 256) {
            int id = node_index[i];
            unsigned rel = (unsigned)(id - lo); // wraps for id<lo / OOR
            if (rel < SLICE_W)
                atomicMin(&ltab[rel], i - start);
        }
        __syncthreads();
        table[(size_t)b * ID_MAX + lo + tid] = ltab[tid];
    } else {
        // ---- pool chunk (pure streaming, boundary-aligned) ----
        const int pid = bid - TB;
        const int b   = pid >> 6;              // / CPG (== 64)
        const int j   = pid & (CPG - 1);
        const int start = ptr[b];
        const int end   = ptr[b + 1];
        const int len   = end - start;
        const int sz    = (len + CPG - 1) / CPG;
        const int r0    = start + j * sz;
        const int r1    = min(r0 + sz, end);

        const int rows_per_iter = 256 / vpr;   // vpr divides 256 (host-checked)
        const int c    = tid & (vpr - 1);
        const int rsub = tid / vpr;

        vf4 acc = 0.0f;
        for (int i = r0 + rsub; i < r1; i += rows_per_iter)
            acc += __builtin_nontemporal_load(&x4[(size_t)i * vpr + c]);
        red[tid] = acc;
        __syncthreads();
        if (rsub == 0) {
            for (int k = 1; k < rows_per_iter; ++k)
                acc += red[k * vpr + c];
            partials[(size_t)pid * vpr + c] = acc;   // plain store
        }
    }
}

// ---------------------------------------------------------------------------
// Kernel B: gather + partial reduce, one launch, independent block roles.
//   blocks [0, B)   : graph_out[b] = sum of b's CPG partials (plain stores,
//                     deterministic order).
//   blocks [B, ...) : table-lookup gather, one vf4 per thread (same logic as
//                     the previously measured gather path).
// ---------------------------------------------------------------------------
__global__ void __launch_bounds__(256)
gather_reduce_kernel(const int* __restrict__ input_ids,
                     const int* __restrict__ table,
                     const vf4* __restrict__ x4,
                     const float* __restrict__ partials,
                     float* __restrict__ graph_out,
                     vf4* __restrict__ out4,
                     int B, int D, int vpr, int vshift, int L,
                     long long total_vec) {
    const int tid = threadIdx.x;
    const int bid = blockIdx.x;

    if (bid < B) {
        // ---- reduce partials for graph bid ----
        const float* p = partials + (size_t)bid * CPG * D;
        for (int d = tid; d < D; d += 256) {
            float s = 0.0f;
            #pragma unroll 4
            for (int j = 0; j < CPG; ++j) s += p[(size_t)j * D + d];
            graph_out[(size_t)bid * D + d] = s;
        }
    } else {
        // ---- gather ----
        long long t = (long long)(bid - B) * 256 + tid;
        if (t >= total_vec) return;
        int row = (int)(t >> vshift);          // flattened (b,l)
        int c   = (int)(t & (vpr - 1));
        int b   = row / L;
        int id  = input_ids[row];
        int m   = (id >= 0 && id < ID_MAX) ? table[(size_t)b * ID_MAX + id]
                                           : INT_MAX;
        vf4 v = 0.0f;
        if (m != INT_MAX)
            v = x4[(long long)m * vpr + c];    // row m used GLOBALLY (faithful
                                               // to reference's quirk)
        __builtin_nontemporal_store(v, &out4[t]);
    }
}

// ---------------------------------------------------------------------------
// Scalar fallback kernels (odd D etc.)
// ---------------------------------------------------------------------------
__device__ __forceinline__ int seg_search(const int* sptr, int B, int i) {
    if (i < sptr[0] || i >= sptr[B]) return -1;
    int lo = 0, hi = B;
    while (hi - lo > 1) {
        int mid = (lo + hi) >> 1;
        if (sptr[mid] <= i) lo = mid; else hi = mid;
    }
    return lo;
}

__global__ void init_kernel(int* __restrict__ table, float* __restrict__ graph_out,
                            int table_n, int graph_n) {
    int i = blockIdx.x * blockDim.x + threadIdx.x;
    if (i < table_n) table[i] = INT_MAX;
    if (i < graph_n) graph_out[i] = 0.0f;
}

__global__ void build_table_kernel(const int* __restrict__ node_index,
                                   const int* __restrict__ ptr,
                                   int* __restrict__ table, int N, int B) {
    __shared__ int sptr[64];
    if (threadIdx.x <= B) sptr[threadIdx.x] = ptr[threadIdx.x];
    __syncthreads();
    int i = blockIdx.x * blockDim.x + threadIdx.x;
    if (i >= N) return;
    int b = seg_search(sptr, B, i);
    if (b < 0) return;
    int m = i - sptr[b];
    int id = node_index[i];
    if (id >= 0 && id < ID_MAX)
        atomicMin(&table[b * ID_MAX + id], m);
}

__global__ void pool1_kernel(const float* __restrict__ x,
                             const int* __restrict__ ptr,
                             float* __restrict__ graph_out,
                             int N, int B, int D, int rows_per_block) {
    __shared__ int sptr[64];
    if (threadIdx.x <= B) sptr[threadIdx.x] = ptr[threadIdx.x];
    __syncthreads();
    int d = threadIdx.x;
    if (d >= D) return;
    int r0 = blockIdx.x * rows_per_block;
    int r1 = min(r0 + rows_per_block, N);
    float acc = 0.0f;
    int accb = -1;
    for (int i = r0; i < r1; ++i) {
        int b = seg_search(sptr, B, i);
        if (b != accb) {
            if (accb >= 0) atomicAdd(&graph_out[(size_t)accb * D + d], acc);
            acc = 0.0f; accb = b;
        }
        if (b >= 0) acc += x[(size_t)i * D + d];
    }
    if (accb >= 0) atomicAdd(&graph_out[(size_t)accb * D + d], acc);
}

__global__ void gather1_kernel(const int* __restrict__ input_ids,
                               const int* __restrict__ table,
                               const float* __restrict__ x,
                               float* __restrict__ seq_out,
                               long long total, int D, int L) {
    long long t = (long long)blockIdx.x * blockDim.x + threadIdx.x;
    if (t >= total) return;
    long long row = t / D;
    int c = (int)(t - row * D);
    int b = (int)(row / L);
    int id = input_ids[row];
    int m  = (id >= 0 && id < ID_MAX) ? table[(size_t)b * ID_MAX + id] : INT_MAX;
    seq_out[t] = (m != INT_MAX) ? x[(long long)m * D + c] : 0.0f;
}

extern "C" void kernel_launch(void* const* d_in, const int* in_sizes, int n_in,
                              void* d_out, int out_size, void* d_ws, size_t ws_size,
                              hipStream_t stream) {
    const int*   input_ids  = (const int*)  d_in[0];   // [B, L]
    const int*   node_index = (const int*)  d_in[1];   // [N]
    const float* x          = (const float*)d_in[2];   // [N, D]
    const int*   ptr        = (const int*)  d_in[3];   // [B+1]

    const int BL = in_sizes[0];
    const int N  = in_sizes[1];
    const int D  = in_sizes[2] / N;
    const int B  = in_sizes[3] - 1;
    const int L  = BL / B;

    float* seq_out   = (float*)d_out;                    // [B*L*D]
    float* graph_out = (float*)d_out + (size_t)BL * D;   // [B*D]
    int*   table     = (int*)d_ws;                       // [B * ID_MAX]
    float* partials  = (float*)d_ws + (size_t)B * ID_MAX; // [B*CPG*D]

    const int vpr = D >> 2;                              // float4 per row
    const bool ws_ok  = ws_size >= ((size_t)B * ID_MAX + (size_t)B * CPG * D)
                                   * sizeof(float);
    const bool vec_ok = ((D & 3) == 0) && (vpr > 0) && (vpr <= 256) &&
                        (256 % vpr == 0) && (B >= 1) && (B <= 63) && ws_ok;

    if (vec_ok) {
        int vshift = 0;
        while ((1 << vshift) < vpr) ++vshift;            // vpr is a power of 2
        const long long total_vec = (long long)BL * vpr;

        // A: table build (B*SLICES blocks) + boundary-aligned pool partials
        //    (B*CPG blocks), independent roles, no ordering requirement.
        table_pool_kernel<<<B * SLICES + B * CPG, 256, 0, stream>>>(
            node_index, ptr, table, (const vf4*)x, (vf4*)partials, B, vpr);

        // B: partial reduce (B blocks) + gather (one vf4/thread).
        const int gather_blocks = (int)((total_vec + 255) / 256);
        gather_reduce_kernel<<<B + gather_blocks, 256, 0, stream>>>(
            input_ids, table, (const vf4*)x, partials, graph_out,
            (vf4*)seq_out, B, D, vpr, vshift, L, total_vec);
    } else {
        const int table_n = B * ID_MAX;
        const int graph_n = B * D;
        const int init_n  = table_n > graph_n ? table_n : graph_n;
        init_kernel<<<(init_n + 255) / 256, 256, 0, stream>>>(table, graph_out,
                                                              table_n, graph_n);
        build_table_kernel<<<(N + 255) / 256, 256, 0, stream>>>(node_index, ptr,
                                                                table, N, B);
        const int rows_per_block = 128;
        const int nchunks = (N + rows_per_block - 1) / rows_per_block;
        int bs = D < 1024 ? ((D + 63) / 64) * 64 : 1024;
        pool1_kernel<<<nchunks, bs, 0, stream>>>(x, ptr, graph_out, N, B, D,
                                                 rows_per_block);
        const long long total = (long long)BL * D;
        const int blocks = (int)((total + 255) / 256);
        gather1_kernel<<<blocks, 256, 0, stream>>>(input_ids, table, x,
                                                   seq_out, total, D, L);
    }
}